// Round 2
// baseline (97.890 us; speedup 1.0000x reference)
//
#include <hip/hip_runtime.h>
#include <math.h>

#define BATCH 4
#define CSEM 512
#define NORG 5
#define NCLS 6
#define HIMG 512
#define WIMG 512
#define HS 32
#define PH 256   // proc spatial (stride-2 conv of 512 with pad 1, k=3)

#define SAG_N (BATCH*CSEM*HS*HS)      // 2097152
#define OH_N  (BATCH*NCLS*HIMG*WIMG)  // 6291456
#define OH_OFF SAG_N
#define XK_OFF (SAG_N + OH_N)

// ---------------- Kernel 1: rasterize one-hot boxes (writes 25MB) -------------
__global__ void k_raster(const int* __restrict__ bb, float* __restrict__ oh) {
    int idx = blockIdx.x * blockDim.x + threadIdx.x;   // B*6*512*128 float4s
    int x4 = (idx & 127) << 2;
    int t  = idx >> 7;
    int y  = t & 511;
    int bc = t >> 9;
    int ch = bc % NCLS;
    int b  = bc / NCLS;
    float4 v = make_float4(0.f, 0.f, 0.f, 0.f);
    if (ch != 0) {
        const int* p = bb + (b * NORG + (ch - 1)) * 4;
        int xmin = min(max(p[0], 0), WIMG - 1);
        int ymin = min(max(p[1], 0), HIMG - 1);
        int xmax = max(xmin, min(p[2], WIMG));
        int ymax = max(ymin, min(p[3], HIMG));
        if (y >= ymin && y < ymax) {
            v.x = (x4 + 0 >= xmin && x4 + 0 < xmax) ? 1.f : 0.f;
            v.y = (x4 + 1 >= xmin && x4 + 1 < xmax) ? 1.f : 0.f;
            v.z = (x4 + 2 >= xmin && x4 + 2 < xmax) ? 1.f : 0.f;
            v.w = (x4 + 3 >= xmin && x4 + 3 < xmax) ? 1.f : 0.f;
        }
    }
    reinterpret_cast<float4*>(oh)[idx] = v;
}

// ---------------- Kernel 2: X_dec_k = bilinear(relu(conv(onehot))) ------------
// Never materializes proc: evaluates conv at the 4 bilinear corners analytically
// from box indicators (separable row/col 3-bit patterns).
__global__ void k_xdeck(const int* __restrict__ bb, const float* __restrict__ Wp,
                        const float* __restrict__ bp, float* __restrict__ xk) {
    int blk = blockIdx.x;            // grid = B*32*8
    int cg = blk & 7;
    int oy = (blk >> 3) & 31;
    int b  = blk >> 8;
    int t  = threadIdx.x;
    int x  = t & 31;
    int c0 = t >> 5;                 // 0..7

    float ysf = (float)(oy * 255.0 / 31.0);
    int y0 = (int)floorf(ysf);
    int y1 = min(y0 + 1, PH - 1);
    float wy = ysf - (float)y0;
    float xsf = (float)(x * 255.0 / 31.0);
    int x0 = (int)floorf(xsf);
    int x1 = min(x0 + 1, PH - 1);
    float wx = xsf - (float)x0;

    float ry0f[NORG][3], ry1f[NORG][3], cx0f[NORG][3], cx1f[NORG][3];
    bool act[NORG];
#pragma unroll
    for (int i = 0; i < NORG; i++) {
        const int* p = bb + (b * NORG + i) * 4;
        int xmin = min(max(p[0], 0), WIMG - 1);
        int ymin = min(max(p[1], 0), HIMG - 1);
        int xmax = max(xmin, min(p[2], WIMG));
        int ymax = max(ymin, min(p[3], HIMG));
        bool anyr = false, anyc = false;
#pragma unroll
        for (int k = 0; k < 3; k++) {
            int r0 = 2 * y0 - 1 + k, r1 = 2 * y1 - 1 + k;
            int cA = 2 * x0 - 1 + k, cB = 2 * x1 - 1 + k;
            float f0 = (r0 >= ymin && r0 < ymax) ? 1.f : 0.f;
            float f1 = (r1 >= ymin && r1 < ymax) ? 1.f : 0.f;
            float g0 = (cA >= xmin && cA < xmax) ? 1.f : 0.f;
            float g1 = (cB >= xmin && cB < xmax) ? 1.f : 0.f;
            ry0f[i][k] = f0; ry1f[i][k] = f1; cx0f[i][k] = g0; cx1f[i][k] = g1;
            anyr = anyr || (f0 > 0.f) || (f1 > 0.f);
            anyc = anyc || (g0 > 0.f) || (g1 > 0.f);
        }
        act[i] = anyr && anyc;
    }

    int cbase = cg * 64 + c0 * 8;
    float P[8][4];
#pragma unroll
    for (int cc = 0; cc < 8; cc++) {
        float bv = bp[cbase + cc];
        P[cc][0] = bv; P[cc][1] = bv; P[cc][2] = bv; P[cc][3] = bv;
    }

#pragma unroll
    for (int i = 0; i < NORG; i++) {
        if (!act[i]) continue;
        float c00 = cx0f[i][0], c01 = cx0f[i][1], c02 = cx0f[i][2];
        float c10 = cx1f[i][0], c11 = cx1f[i][1], c12 = cx1f[i][2];
        float r00 = ry0f[i][0], r01 = ry0f[i][1], r02 = ry0f[i][2];
        float r10 = ry1f[i][0], r11 = ry1f[i][1], r12 = ry1f[i][2];
#pragma unroll
        for (int cc = 0; cc < 8; cc++) {
            const float* w = Wp + (size_t)((cbase + cc) * NCLS + i + 1) * 9;
            float w0 = w[0], w1 = w[1], w2 = w[2];
            float w3 = w[3], w4 = w[4], w5 = w[5];
            float w6 = w[6], w7 = w[7], w8 = w[8];
            float s00 = w0 * c00 + w1 * c01 + w2 * c02;
            float s01 = w3 * c00 + w4 * c01 + w5 * c02;
            float s02 = w6 * c00 + w7 * c01 + w8 * c02;
            float s10 = w0 * c10 + w1 * c11 + w2 * c12;
            float s11 = w3 * c10 + w4 * c11 + w5 * c12;
            float s12 = w6 * c10 + w7 * c11 + w8 * c12;
            P[cc][0] += s00 * r00 + s01 * r01 + s02 * r02;  // (y0,x0)
            P[cc][1] += s10 * r00 + s11 * r01 + s12 * r02;  // (y0,x1)
            P[cc][2] += s00 * r10 + s01 * r11 + s02 * r12;  // (y1,x0)
            P[cc][3] += s10 * r10 + s11 * r11 + s12 * r12;  // (y1,x1)
        }
    }

#pragma unroll
    for (int cc = 0; cc < 8; cc++) {
        int c = cbase + cc;
        float p00 = fmaxf(P[cc][0], 0.f);
        float p01 = fmaxf(P[cc][1], 0.f);
        float p10 = fmaxf(P[cc][2], 0.f);
        float p11 = fmaxf(P[cc][3], 0.f);
        float t0 = p00 * (1.f - wy) + p10 * wy;
        float t1 = p01 * (1.f - wy) + p11 * wy;
        float val = t0 * (1.f - wx) + t1 * wx;
        xk[((b * CSEM + c) * HS + oy) * HS + x] = val;
    }
}

// ---------------- Kernel 3a: alpha logit partials (channel reduction) ---------
__global__ void k_logits(const float* __restrict__ enc, const float* __restrict__ xk,
                         const float* __restrict__ Wa, float* __restrict__ part) {
    int blk = blockIdx.x;            // grid = B*32*4
    int cg = blk & 3;
    int oy = (blk >> 2) & 31;
    int b  = blk >> 7;
    int t  = threadIdx.x;
    int x  = t & 31;
    int c0 = t >> 5;                 // 0..7
    float acc[NCLS] = {0, 0, 0, 0, 0, 0};
    for (int k = 0; k < 16; k++) {
        int c = cg * 128 + k * 8 + c0;
        int idx = ((b * CSEM + c) * HS + oy) * HS + x;
        float att = enc[idx] * xk[idx];
#pragma unroll
        for (int o = 0; o < NCLS; o++) acc[o] += Wa[o * CSEM + c] * att;
    }
    __shared__ float red[NCLS][8][32];
#pragma unroll
    for (int o = 0; o < NCLS; o++) red[o][c0][x] = acc[o];
    __syncthreads();
    if (t < NCLS * 32) {
        int o = t >> 5;
        int xx = t & 31;
        float s = 0.f;
#pragma unroll
        for (int j = 0; j < 8; j++) s += red[o][j][xx];
        part[(((cg * BATCH + b) * NCLS + o) * HS + oy) * HS + xx] = s;
    }
}

// ---------------- Kernel 3b: 6-way softmax ------------------------------------
__global__ void k_softmax(const float* __restrict__ part, float* __restrict__ alpha) {
    int idx = blockIdx.x * blockDim.x + threadIdx.x;   // B*32*32 = 4096
    if (idx >= BATCH * HS * HS) return;
    int x = idx & 31, oy = (idx >> 5) & 31, b = idx >> 10;
    float l[NCLS];
#pragma unroll
    for (int o = 0; o < NCLS; o++) {
        float s = 0.f;
#pragma unroll
        for (int cg = 0; cg < 4; cg++)
            s += part[(((cg * BATCH + b) * NCLS + o) * HS + oy) * HS + x];
        l[o] = s;
    }
    float m = l[0];
#pragma unroll
    for (int o = 1; o < NCLS; o++) m = fmaxf(m, l[o]);
    float sum = 0.f;
#pragma unroll
    for (int o = 0; o < NCLS; o++) { l[o] = expf(l[o] - m); sum += l[o]; }
    float inv = 1.f / sum;
#pragma unroll
    for (int o = 0; o < NCLS; o++)
        alpha[((b * NCLS + o) * HS + oy) * HS + x] = l[o] * inv;
}

// ---------------- Kernel 4: sag gate (elementwise) ----------------------------
__global__ void k_sag(const float* __restrict__ enc, const float* __restrict__ We,
                      const float* __restrict__ alpha, float* __restrict__ out) {
    int idx = blockIdx.x * blockDim.x + threadIdx.x;   // SAG_N/4 = 524288
    int x4 = (idx & 7) << 2;
    int oy = (idx >> 3) & 31;
    int c  = (idx >> 8) & 511;
    int b  = idx >> 17;
    float4 e = reinterpret_cast<const float4*>(enc)[idx];
    float4 ae = make_float4(0.f, 0.f, 0.f, 0.f);
#pragma unroll
    for (int o = 0; o < NCLS; o++) {
        float w = We[c * NCLS + o];
        const float4 a = *reinterpret_cast<const float4*>(
            alpha + ((b * NCLS + o) * HS + oy) * HS + x4);
        ae.x += w * a.x; ae.y += w * a.y; ae.z += w * a.z; ae.w += w * a.w;
    }
    float4 r;
    r.x = e.x + 1.f / (1.f + expf(-e.x * ae.x));
    r.y = e.y + 1.f / (1.f + expf(-e.y * ae.y));
    r.z = e.z + 1.f / (1.f + expf(-e.z * ae.z));
    r.w = e.w + 1.f / (1.f + expf(-e.w * ae.w));
    reinterpret_cast<float4*>(out)[idx] = r;
}

extern "C" void kernel_launch(void* const* d_in, const int* in_sizes, int n_in,
                              void* d_out, int out_size, void* d_ws, size_t ws_size,
                              hipStream_t stream) {
    const float* enc = (const float*)d_in[0];
    const int*   bb  = (const int*)d_in[1];
    const float* Wp  = (const float*)d_in[2];
    const float* bp  = (const float*)d_in[3];
    const float* Wa  = (const float*)d_in[4];
    const float* We  = (const float*)d_in[5];
    float* out = (float*)d_out;
    float* sag = out;
    float* oh  = out + OH_OFF;
    float* xk  = out + XK_OFF;
    // Scratch lives inside the one_hot output region; rasterize runs LAST and
    // overwrites it completely.
    float* part  = oh;                       // 4*B*6*32*32 = 98304 floats
    float* alpha = oh + 98304;               // B*6*32*32   = 24576 floats

    k_xdeck  <<<BATCH * 32 * 8, 256, 0, stream>>>(bb, Wp, bp, xk);
    k_logits <<<BATCH * 32 * 4, 256, 0, stream>>>(enc, xk, Wa, part);
    k_softmax<<<16, 256, 0, stream>>>(part, alpha);
    k_sag    <<<SAG_N / 4 / 256, 256, 0, stream>>>(enc, We, alpha, sag);
    k_raster <<<OH_N / 4 / 256, 256, 0, stream>>>(bb, oh);
}

// Round 3
// 94.677 us; speedup vs baseline: 1.0339x; 1.0339x over previous
//
#include <hip/hip_runtime.h>
#include <math.h>

#define BATCH 4
#define CSEM 512
#define NORG 5
#define NCLS 6
#define HIMG 512
#define WIMG 512
#define HS 32
#define PH 256   // proc spatial (stride-2 conv of 512 with pad 1, k=3)

#define SAG_N (BATCH*CSEM*HS*HS)      // 2097152
#define OH_N  (BATCH*NCLS*HIMG*WIMG)  // 6291456
#define OH_OFF SAG_N
#define XK_OFF (SAG_N + OH_N)

// ---------------- Kernel 1: fused xdeck + alpha-logit partials ----------------
// Computes X_dec_k = bilinear(relu(conv(onehot))) analytically from box
// indicators (never materializing proc OR onehot), writes xk, and immediately
// reduces the per-channel attended product into 6 alpha-logit partials.
__global__ void k_xdeck_logits(const int* __restrict__ bb, const float* __restrict__ Wp,
                               const float* __restrict__ bp, const float* __restrict__ enc,
                               const float* __restrict__ Wa, float* __restrict__ xk,
                               float* __restrict__ part) {
    int blk = blockIdx.x;            // grid = B*32*8
    int cg = blk & 7;
    int oy = (blk >> 3) & 31;
    int b  = blk >> 8;
    int t  = threadIdx.x;
    int x  = t & 31;
    int c0 = t >> 5;                 // 0..7

    float ysf = (float)(oy * 255.0 / 31.0);
    int y0 = (int)floorf(ysf);
    int y1 = min(y0 + 1, PH - 1);
    float wy = ysf - (float)y0;
    float xsf = (float)(x * 255.0 / 31.0);
    int x0 = (int)floorf(xsf);
    int x1 = min(x0 + 1, PH - 1);
    float wx = xsf - (float)x0;

    float ry0f[NORG][3], ry1f[NORG][3], cx0f[NORG][3], cx1f[NORG][3];
    bool act[NORG];
#pragma unroll
    for (int i = 0; i < NORG; i++) {
        const int* p = bb + (b * NORG + i) * 4;
        int xmin = min(max(p[0], 0), WIMG - 1);
        int ymin = min(max(p[1], 0), HIMG - 1);
        int xmax = max(xmin, min(p[2], WIMG));
        int ymax = max(ymin, min(p[3], HIMG));
        bool anyr = false, anyc = false;
#pragma unroll
        for (int k = 0; k < 3; k++) {
            int r0 = 2 * y0 - 1 + k, r1 = 2 * y1 - 1 + k;
            int cA = 2 * x0 - 1 + k, cB = 2 * x1 - 1 + k;
            float f0 = (r0 >= ymin && r0 < ymax) ? 1.f : 0.f;
            float f1 = (r1 >= ymin && r1 < ymax) ? 1.f : 0.f;
            float g0 = (cA >= xmin && cA < xmax) ? 1.f : 0.f;
            float g1 = (cB >= xmin && cB < xmax) ? 1.f : 0.f;
            ry0f[i][k] = f0; ry1f[i][k] = f1; cx0f[i][k] = g0; cx1f[i][k] = g1;
            anyr = anyr || (f0 > 0.f) || (f1 > 0.f);
            anyc = anyc || (g0 > 0.f) || (g1 > 0.f);
        }
        act[i] = anyr && anyc;
    }

    int cbase = cg * 64 + c0 * 8;
    float P[8][4];
#pragma unroll
    for (int cc = 0; cc < 8; cc++) {
        float bv = bp[cbase + cc];
        P[cc][0] = bv; P[cc][1] = bv; P[cc][2] = bv; P[cc][3] = bv;
    }

#pragma unroll
    for (int i = 0; i < NORG; i++) {
        if (!act[i]) continue;
        float c00 = cx0f[i][0], c01 = cx0f[i][1], c02 = cx0f[i][2];
        float c10 = cx1f[i][0], c11 = cx1f[i][1], c12 = cx1f[i][2];
        float r00 = ry0f[i][0], r01 = ry0f[i][1], r02 = ry0f[i][2];
        float r10 = ry1f[i][0], r11 = ry1f[i][1], r12 = ry1f[i][2];
#pragma unroll
        for (int cc = 0; cc < 8; cc++) {
            const float* w = Wp + (size_t)((cbase + cc) * NCLS + i + 1) * 9;
            float w0 = w[0], w1 = w[1], w2 = w[2];
            float w3 = w[3], w4 = w[4], w5 = w[5];
            float w6 = w[6], w7 = w[7], w8 = w[8];
            float s00 = w0 * c00 + w1 * c01 + w2 * c02;
            float s01 = w3 * c00 + w4 * c01 + w5 * c02;
            float s02 = w6 * c00 + w7 * c01 + w8 * c02;
            float s10 = w0 * c10 + w1 * c11 + w2 * c12;
            float s11 = w3 * c10 + w4 * c11 + w5 * c12;
            float s12 = w6 * c10 + w7 * c11 + w8 * c12;
            P[cc][0] += s00 * r00 + s01 * r01 + s02 * r02;  // (y0,x0)
            P[cc][1] += s10 * r00 + s11 * r01 + s12 * r02;  // (y0,x1)
            P[cc][2] += s00 * r10 + s01 * r11 + s02 * r12;  // (y1,x0)
            P[cc][3] += s10 * r10 + s11 * r11 + s12 * r12;  // (y1,x1)
        }
    }

    float acc[NCLS] = {0, 0, 0, 0, 0, 0};
#pragma unroll
    for (int cc = 0; cc < 8; cc++) {
        int c = cbase + cc;
        float p00 = fmaxf(P[cc][0], 0.f);
        float p01 = fmaxf(P[cc][1], 0.f);
        float p10 = fmaxf(P[cc][2], 0.f);
        float p11 = fmaxf(P[cc][3], 0.f);
        float t0 = p00 * (1.f - wy) + p10 * wy;
        float t1 = p01 * (1.f - wy) + p11 * wy;
        float val = t0 * (1.f - wx) + t1 * wx;
        int idx = ((b * CSEM + c) * HS + oy) * HS + x;
        xk[idx] = val;
        float att = enc[idx] * val;
#pragma unroll
        for (int o = 0; o < NCLS; o++) acc[o] += Wa[o * CSEM + c] * att;
    }

    __shared__ float red[NCLS][8][32];
#pragma unroll
    for (int o = 0; o < NCLS; o++) red[o][c0][x] = acc[o];
    __syncthreads();
    if (t < NCLS * 32) {
        int o = t >> 5;
        int xx = t & 31;
        float s = 0.f;
#pragma unroll
        for (int j = 0; j < 8; j++) s += red[o][j][xx];
        part[(((cg * BATCH + b) * NCLS + o) * HS + oy) * HS + xx] = s;
    }
}

// ---------------- Kernel 2: fused softmax + sag gate --------------------------
// Each block recomputes the tiny 6-way softmax for its (b,oy) row from the
// partials (L2-hit), then streams its channel slice of enc -> sag output.
__global__ void k_softmax_sag(const float* __restrict__ part, const float* __restrict__ enc,
                              const float* __restrict__ We, float* __restrict__ out) {
    int blk = blockIdx.x;            // grid = B*32*4
    int sl = blk & 3;                // channel slice of 128
    int oy = (blk >> 2) & 31;
    int b  = blk >> 7;
    int t  = threadIdx.x;

    __shared__ float lg[NCLS][32];
    if (t < NCLS * 32) {
        int o = t >> 5;
        int x = t & 31;
        float s = 0.f;
#pragma unroll
        for (int cg = 0; cg < 8; cg++)
            s += part[(((cg * BATCH + b) * NCLS + o) * HS + oy) * HS + x];
        lg[o][x] = s;
    }
    __syncthreads();
    if (t < 32) {
        float l[NCLS];
#pragma unroll
        for (int o = 0; o < NCLS; o++) l[o] = lg[o][t];
        float m = l[0];
#pragma unroll
        for (int o = 1; o < NCLS; o++) m = fmaxf(m, l[o]);
        float sum = 0.f;
#pragma unroll
        for (int o = 0; o < NCLS; o++) { l[o] = expf(l[o] - m); sum += l[o]; }
        float inv = 1.f / sum;
#pragma unroll
        for (int o = 0; o < NCLS; o++) lg[o][t] = l[o] * inv;
    }
    __syncthreads();

    int x4 = (t & 7) << 2;           // float4 along x
    int cq = t >> 3;                 // 0..31
#pragma unroll
    for (int j = 0; j < 4; j++) {
        int c = sl * 128 + cq * 4 + j;
        int idx4 = (((b * CSEM + c) * HS + oy) * HS + x4) >> 2;
        float4 e = reinterpret_cast<const float4*>(enc)[idx4];
        float4 ae = make_float4(0.f, 0.f, 0.f, 0.f);
#pragma unroll
        for (int o = 0; o < NCLS; o++) {
            float w = We[c * NCLS + o];
            ae.x += w * lg[o][x4 + 0];
            ae.y += w * lg[o][x4 + 1];
            ae.z += w * lg[o][x4 + 2];
            ae.w += w * lg[o][x4 + 3];
        }
        float4 r;
        r.x = e.x + 1.f / (1.f + expf(-e.x * ae.x));
        r.y = e.y + 1.f / (1.f + expf(-e.y * ae.y));
        r.z = e.z + 1.f / (1.f + expf(-e.z * ae.z));
        r.w = e.w + 1.f / (1.f + expf(-e.w * ae.w));
        reinterpret_cast<float4*>(out)[idx4] = r;
    }
}

// ---------------- Kernel 3: rasterize one-hot boxes (writes 25MB) -------------
__global__ void k_raster(const int* __restrict__ bb, float* __restrict__ oh) {
    int idx = blockIdx.x * blockDim.x + threadIdx.x;   // B*6*512*128 float4s
    int x4 = (idx & 127) << 2;
    int t  = idx >> 7;
    int y  = t & 511;
    int bc = t >> 9;
    int ch = bc % NCLS;
    int b  = bc / NCLS;
    float4 v = make_float4(0.f, 0.f, 0.f, 0.f);
    if (ch != 0) {
        const int* p = bb + (b * NORG + (ch - 1)) * 4;
        int xmin = min(max(p[0], 0), WIMG - 1);
        int ymin = min(max(p[1], 0), HIMG - 1);
        int xmax = max(xmin, min(p[2], WIMG));
        int ymax = max(ymin, min(p[3], HIMG));
        if (y >= ymin && y < ymax) {
            v.x = (x4 + 0 >= xmin && x4 + 0 < xmax) ? 1.f : 0.f;
            v.y = (x4 + 1 >= xmin && x4 + 1 < xmax) ? 1.f : 0.f;
            v.z = (x4 + 2 >= xmin && x4 + 2 < xmax) ? 1.f : 0.f;
            v.w = (x4 + 3 >= xmin && x4 + 3 < xmax) ? 1.f : 0.f;
        }
    }
    reinterpret_cast<float4*>(oh)[idx] = v;
}

extern "C" void kernel_launch(void* const* d_in, const int* in_sizes, int n_in,
                              void* d_out, int out_size, void* d_ws, size_t ws_size,
                              hipStream_t stream) {
    const float* enc = (const float*)d_in[0];
    const int*   bb  = (const int*)d_in[1];
    const float* Wp  = (const float*)d_in[2];
    const float* bp  = (const float*)d_in[3];
    const float* Wa  = (const float*)d_in[4];
    const float* We  = (const float*)d_in[5];
    float* out = (float*)d_out;
    float* sag = out;
    float* oh  = out + OH_OFF;
    float* xk  = out + XK_OFF;
    // Scratch (logit partials) lives inside the one_hot output region;
    // rasterize runs LAST and overwrites it completely.
    float* part = oh;                        // 8*B*6*32*32 = 196608 floats

    k_xdeck_logits<<<BATCH * 32 * 8, 256, 0, stream>>>(bb, Wp, bp, enc, Wa, xk, part);
    k_softmax_sag <<<BATCH * 32 * 4, 256, 0, stream>>>(part, enc, We, sag);
    k_raster      <<<OH_N / 4 / 256, 256, 0, stream>>>(bb, oh);
}

// Round 4
// 94.095 us; speedup vs baseline: 1.0403x; 1.0062x over previous
//
#include <hip/hip_runtime.h>
#include <math.h>

#define BATCH 4
#define CSEM 512
#define NORG 5
#define NCLS 6
#define HIMG 512
#define WIMG 512
#define HS 32
#define PH 256   // proc spatial (stride-2 conv of 512 with pad 1, k=3)

#define SAG_N (BATCH*CSEM*HS*HS)      // 2097152
#define OH_N  (BATCH*NCLS*HIMG*WIMG)  // 6291456
#define OH_OFF SAG_N
#define XK_OFF (SAG_N + OH_N)
#define RASTER_BLOCKS (OH_N / 4 / 256)   // 6144
#define SAG_BLOCKS    (BATCH * 32 * 4)   // 512

// ---------------- Kernel 1: fused xdeck + alpha-logit partials ----------------
// Computes X_dec_k = bilinear(relu(conv(onehot))) analytically from box
// indicators (never materializing proc OR onehot), writes xk, and immediately
// reduces the per-channel attended product into 6 alpha-logit partials (d_ws).
__global__ void k_xdeck_logits(const int* __restrict__ bb, const float* __restrict__ Wp,
                               const float* __restrict__ bp, const float* __restrict__ enc,
                               const float* __restrict__ Wa, float* __restrict__ xk,
                               float* __restrict__ part) {
    int blk = blockIdx.x;            // grid = B*32*8
    int cg = blk & 7;
    int oy = (blk >> 3) & 31;
    int b  = blk >> 8;
    int t  = threadIdx.x;
    int x  = t & 31;
    int c0 = t >> 5;                 // 0..7

    float ysf = (float)(oy * 255.0 / 31.0);
    int y0 = (int)floorf(ysf);
    int y1 = min(y0 + 1, PH - 1);
    float wy = ysf - (float)y0;
    float xsf = (float)(x * 255.0 / 31.0);
    int x0 = (int)floorf(xsf);
    int x1 = min(x0 + 1, PH - 1);
    float wx = xsf - (float)x0;

    float ry0f[NORG][3], ry1f[NORG][3], cx0f[NORG][3], cx1f[NORG][3];
    bool act[NORG];
#pragma unroll
    for (int i = 0; i < NORG; i++) {
        const int* p = bb + (b * NORG + i) * 4;
        int xmin = min(max(p[0], 0), WIMG - 1);
        int ymin = min(max(p[1], 0), HIMG - 1);
        int xmax = max(xmin, min(p[2], WIMG));
        int ymax = max(ymin, min(p[3], HIMG));
        bool anyr = false, anyc = false;
#pragma unroll
        for (int k = 0; k < 3; k++) {
            int r0 = 2 * y0 - 1 + k, r1 = 2 * y1 - 1 + k;
            int cA = 2 * x0 - 1 + k, cB = 2 * x1 - 1 + k;
            float f0 = (r0 >= ymin && r0 < ymax) ? 1.f : 0.f;
            float f1 = (r1 >= ymin && r1 < ymax) ? 1.f : 0.f;
            float g0 = (cA >= xmin && cA < xmax) ? 1.f : 0.f;
            float g1 = (cB >= xmin && cB < xmax) ? 1.f : 0.f;
            ry0f[i][k] = f0; ry1f[i][k] = f1; cx0f[i][k] = g0; cx1f[i][k] = g1;
            anyr = anyr || (f0 > 0.f) || (f1 > 0.f);
            anyc = anyc || (g0 > 0.f) || (g1 > 0.f);
        }
        act[i] = anyr && anyc;
    }

    int cbase = cg * 64 + c0 * 8;
    float P[8][4];
#pragma unroll
    for (int cc = 0; cc < 8; cc++) {
        float bv = bp[cbase + cc];
        P[cc][0] = bv; P[cc][1] = bv; P[cc][2] = bv; P[cc][3] = bv;
    }

#pragma unroll
    for (int i = 0; i < NORG; i++) {
        if (!act[i]) continue;
        float c00 = cx0f[i][0], c01 = cx0f[i][1], c02 = cx0f[i][2];
        float c10 = cx1f[i][0], c11 = cx1f[i][1], c12 = cx1f[i][2];
        float r00 = ry0f[i][0], r01 = ry0f[i][1], r02 = ry0f[i][2];
        float r10 = ry1f[i][0], r11 = ry1f[i][1], r12 = ry1f[i][2];
#pragma unroll
        for (int cc = 0; cc < 8; cc++) {
            const float* w = Wp + (size_t)((cbase + cc) * NCLS + i + 1) * 9;
            float w0 = w[0], w1 = w[1], w2 = w[2];
            float w3 = w[3], w4 = w[4], w5 = w[5];
            float w6 = w[6], w7 = w[7], w8 = w[8];
            float s00 = w0 * c00 + w1 * c01 + w2 * c02;
            float s01 = w3 * c00 + w4 * c01 + w5 * c02;
            float s02 = w6 * c00 + w7 * c01 + w8 * c02;
            float s10 = w0 * c10 + w1 * c11 + w2 * c12;
            float s11 = w3 * c10 + w4 * c11 + w5 * c12;
            float s12 = w6 * c10 + w7 * c11 + w8 * c12;
            P[cc][0] += s00 * r00 + s01 * r01 + s02 * r02;  // (y0,x0)
            P[cc][1] += s10 * r00 + s11 * r01 + s12 * r02;  // (y0,x1)
            P[cc][2] += s00 * r10 + s01 * r11 + s02 * r12;  // (y1,x0)
            P[cc][3] += s10 * r10 + s11 * r11 + s12 * r12;  // (y1,x1)
        }
    }

    float acc[NCLS] = {0, 0, 0, 0, 0, 0};
#pragma unroll
    for (int cc = 0; cc < 8; cc++) {
        int c = cbase + cc;
        float p00 = fmaxf(P[cc][0], 0.f);
        float p01 = fmaxf(P[cc][1], 0.f);
        float p10 = fmaxf(P[cc][2], 0.f);
        float p11 = fmaxf(P[cc][3], 0.f);
        float t0 = p00 * (1.f - wy) + p10 * wy;
        float t1 = p01 * (1.f - wy) + p11 * wy;
        float val = t0 * (1.f - wx) + t1 * wx;
        int idx = ((b * CSEM + c) * HS + oy) * HS + x;
        xk[idx] = val;
        float att = enc[idx] * val;
#pragma unroll
        for (int o = 0; o < NCLS; o++) acc[o] += Wa[o * CSEM + c] * att;
    }

    __shared__ float red[NCLS][8][32];
#pragma unroll
    for (int o = 0; o < NCLS; o++) red[o][c0][x] = acc[o];
    __syncthreads();
    if (t < NCLS * 32) {
        int o = t >> 5;
        int xx = t & 31;
        float s = 0.f;
#pragma unroll
        for (int j = 0; j < 8; j++) s += red[o][j][xx];
        part[(((cg * BATCH + b) * NCLS + o) * HS + oy) * HS + xx] = s;
    }
}

// ------- Kernel 2: raster (blocks 0..6143) + softmax+sag (blocks 6144..) -----
// Raster is pure store-bound; softmax+sag is read+compute — co-scheduling them
// in one dispatch overlaps the pipes and drops a launch.
__global__ void k_sag_raster(const float* __restrict__ part, const float* __restrict__ enc,
                             const float* __restrict__ We, const int* __restrict__ bb,
                             float* __restrict__ out, float* __restrict__ oh) {
    int blk = blockIdx.x;
    int t = threadIdx.x;

    if (blk < RASTER_BLOCKS) {
        int idx = blk * 256 + t;         // B*6*512*128 float4s
        int x4 = (idx & 127) << 2;
        int tt = idx >> 7;
        int y  = tt & 511;
        int bc = tt >> 9;
        int ch = bc % NCLS;
        int b  = bc / NCLS;
        float4 v = make_float4(0.f, 0.f, 0.f, 0.f);
        if (ch != 0) {
            const int* p = bb + (b * NORG + (ch - 1)) * 4;
            int xmin = min(max(p[0], 0), WIMG - 1);
            int ymin = min(max(p[1], 0), HIMG - 1);
            int xmax = max(xmin, min(p[2], WIMG));
            int ymax = max(ymin, min(p[3], HIMG));
            if (y >= ymin && y < ymax) {
                v.x = (x4 + 0 >= xmin && x4 + 0 < xmax) ? 1.f : 0.f;
                v.y = (x4 + 1 >= xmin && x4 + 1 < xmax) ? 1.f : 0.f;
                v.z = (x4 + 2 >= xmin && x4 + 2 < xmax) ? 1.f : 0.f;
                v.w = (x4 + 3 >= xmin && x4 + 3 < xmax) ? 1.f : 0.f;
            }
        }
        reinterpret_cast<float4*>(oh)[idx] = v;
        return;
    }

    blk -= RASTER_BLOCKS;                // grid = B*32*4
    int sl = blk & 3;                    // channel slice of 128
    int oy = (blk >> 2) & 31;
    int b  = blk >> 7;

    __shared__ float lg[NCLS][32];
    if (t < NCLS * 32) {
        int o = t >> 5;
        int x = t & 31;
        float s = 0.f;
#pragma unroll
        for (int cg = 0; cg < 8; cg++)
            s += part[(((cg * BATCH + b) * NCLS + o) * HS + oy) * HS + x];
        lg[o][x] = s;
    }
    __syncthreads();
    if (t < 32) {
        float l[NCLS];
#pragma unroll
        for (int o = 0; o < NCLS; o++) l[o] = lg[o][t];
        float m = l[0];
#pragma unroll
        for (int o = 1; o < NCLS; o++) m = fmaxf(m, l[o]);
        float sum = 0.f;
#pragma unroll
        for (int o = 0; o < NCLS; o++) { l[o] = expf(l[o] - m); sum += l[o]; }
        float inv = 1.f / sum;
#pragma unroll
        for (int o = 0; o < NCLS; o++) lg[o][t] = l[o] * inv;
    }
    __syncthreads();

    int x4 = (t & 7) << 2;               // float4 along x
    int cq = t >> 3;                     // 0..31
#pragma unroll
    for (int j = 0; j < 4; j++) {
        int c = sl * 128 + cq * 4 + j;
        int idx4 = (((b * CSEM + c) * HS + oy) * HS + x4) >> 2;
        float4 e = reinterpret_cast<const float4*>(enc)[idx4];
        float4 ae = make_float4(0.f, 0.f, 0.f, 0.f);
#pragma unroll
        for (int o = 0; o < NCLS; o++) {
            float w = We[c * NCLS + o];
            ae.x += w * lg[o][x4 + 0];
            ae.y += w * lg[o][x4 + 1];
            ae.z += w * lg[o][x4 + 2];
            ae.w += w * lg[o][x4 + 3];
        }
        float4 r;
        r.x = e.x + 1.f / (1.f + expf(-e.x * ae.x));
        r.y = e.y + 1.f / (1.f + expf(-e.y * ae.y));
        r.z = e.z + 1.f / (1.f + expf(-e.z * ae.z));
        r.w = e.w + 1.f / (1.f + expf(-e.w * ae.w));
        reinterpret_cast<float4*>(out)[idx4] = r;
    }
}

extern "C" void kernel_launch(void* const* d_in, const int* in_sizes, int n_in,
                              void* d_out, int out_size, void* d_ws, size_t ws_size,
                              hipStream_t stream) {
    const float* enc = (const float*)d_in[0];
    const int*   bb  = (const int*)d_in[1];
    const float* Wp  = (const float*)d_in[2];
    const float* bp  = (const float*)d_in[3];
    const float* Wa  = (const float*)d_in[4];
    const float* We  = (const float*)d_in[5];
    float* out = (float*)d_out;
    float* sag = out;
    float* oh  = out + OH_OFF;
    float* xk  = out + XK_OFF;
    // Logit partials live in d_ws (fully rewritten every call, so the 0xAA
    // poison is harmless); this frees raster to run concurrently with sag.
    float* part = (float*)d_ws;              // 8*B*6*32*32 = 196608 floats

    k_xdeck_logits<<<BATCH * 32 * 8, 256, 0, stream>>>(bb, Wp, bp, enc, Wa, xk, part);
    k_sag_raster  <<<RASTER_BLOCKS + SAG_BLOCKS, 256, 0, stream>>>(part, enc, We, bb, sag, oh);
}

// Round 5
// 89.844 us; speedup vs baseline: 1.0896x; 1.0473x over previous
//
#include <hip/hip_runtime.h>
#include <math.h>

#define BATCH 4
#define CSEM 512
#define NORG 5
#define NCLS 6
#define HIMG 512
#define WIMG 512
#define HS 32
#define PH 256   // proc spatial (stride-2 conv of 512 with pad 1, k=3)

#define SAG_N (BATCH*CSEM*HS*HS)      // 2097152
#define OH_N  (BATCH*NCLS*HIMG*WIMG)  // 6291456
#define OH_OFF SAG_N
#define XK_OFF (SAG_N + OH_N)
#define XDECK_BLOCKS  (BATCH * 32 * 8)   // 1024
#define RASTER_BLOCKS (OH_N / 4 / 256)   // 6144

// ------- Kernel 1: xdeck+logits (blocks 0..1023) || raster (1024..7167) -------
// xdeck is VALU/latency-bound, raster is pure store-BW-bound; co-dispatching
// them in one kernel overlaps the two pipes. Raster has no dependency on
// anything computed here (reads only bboxes).
__global__ void k_xdeck_raster(const int* __restrict__ bb, const float* __restrict__ Wp,
                               const float* __restrict__ bp, const float* __restrict__ enc,
                               const float* __restrict__ Wa, float* __restrict__ xk,
                               float* __restrict__ part, float* __restrict__ oh) {
    int blk = blockIdx.x;
    int t = threadIdx.x;

    if (blk >= XDECK_BLOCKS) {
        // ---------------- raster: one-hot box rasterization (25MB stores) -----
        int idx = (blk - XDECK_BLOCKS) * 256 + t;   // B*6*512*128 float4s
        int x4 = (idx & 127) << 2;
        int tt = idx >> 7;
        int y  = tt & 511;
        int bc = tt >> 9;
        int ch = bc % NCLS;
        int b  = bc / NCLS;
        float4 v = make_float4(0.f, 0.f, 0.f, 0.f);
        if (ch != 0) {
            const int* p = bb + (b * NORG + (ch - 1)) * 4;
            int xmin = min(max(p[0], 0), WIMG - 1);
            int ymin = min(max(p[1], 0), HIMG - 1);
            int xmax = max(xmin, min(p[2], WIMG));
            int ymax = max(ymin, min(p[3], HIMG));
            if (y >= ymin && y < ymax) {
                v.x = (x4 + 0 >= xmin && x4 + 0 < xmax) ? 1.f : 0.f;
                v.y = (x4 + 1 >= xmin && x4 + 1 < xmax) ? 1.f : 0.f;
                v.z = (x4 + 2 >= xmin && x4 + 2 < xmax) ? 1.f : 0.f;
                v.w = (x4 + 3 >= xmin && x4 + 3 < xmax) ? 1.f : 0.f;
            }
        }
        reinterpret_cast<float4*>(oh)[idx] = v;
        return;
    }

    // ---------------- xdeck + alpha-logit partials ----------------------------
    int cg = blk & 7;
    int oy = (blk >> 3) & 31;
    int b  = blk >> 8;
    int x  = t & 31;
    int c0 = t >> 5;                 // 0..7

    float ysf = (float)(oy * 255.0 / 31.0);
    int y0 = (int)floorf(ysf);
    int y1 = min(y0 + 1, PH - 1);
    float wy = ysf - (float)y0;
    float xsf = (float)(x * 255.0 / 31.0);
    int x0 = (int)floorf(xsf);
    int x1 = min(x0 + 1, PH - 1);
    float wx = xsf - (float)x0;

    float ry0f[NORG][3], ry1f[NORG][3], cx0f[NORG][3], cx1f[NORG][3];
    bool act[NORG];
#pragma unroll
    for (int i = 0; i < NORG; i++) {
        const int* p = bb + (b * NORG + i) * 4;
        int xmin = min(max(p[0], 0), WIMG - 1);
        int ymin = min(max(p[1], 0), HIMG - 1);
        int xmax = max(xmin, min(p[2], WIMG));
        int ymax = max(ymin, min(p[3], HIMG));
        bool anyr = false, anyc = false;
#pragma unroll
        for (int k = 0; k < 3; k++) {
            int r0 = 2 * y0 - 1 + k, r1 = 2 * y1 - 1 + k;
            int cA = 2 * x0 - 1 + k, cB = 2 * x1 - 1 + k;
            float f0 = (r0 >= ymin && r0 < ymax) ? 1.f : 0.f;
            float f1 = (r1 >= ymin && r1 < ymax) ? 1.f : 0.f;
            float g0 = (cA >= xmin && cA < xmax) ? 1.f : 0.f;
            float g1 = (cB >= xmin && cB < xmax) ? 1.f : 0.f;
            ry0f[i][k] = f0; ry1f[i][k] = f1; cx0f[i][k] = g0; cx1f[i][k] = g1;
            anyr = anyr || (f0 > 0.f) || (f1 > 0.f);
            anyc = anyc || (g0 > 0.f) || (g1 > 0.f);
        }
        act[i] = anyr && anyc;
    }

    int cbase = cg * 64 + c0 * 8;
    float P[8][4];
#pragma unroll
    for (int cc = 0; cc < 8; cc++) {
        float bv = bp[cbase + cc];
        P[cc][0] = bv; P[cc][1] = bv; P[cc][2] = bv; P[cc][3] = bv;
    }

#pragma unroll
    for (int i = 0; i < NORG; i++) {
        if (!act[i]) continue;
        float c00 = cx0f[i][0], c01 = cx0f[i][1], c02 = cx0f[i][2];
        float c10 = cx1f[i][0], c11 = cx1f[i][1], c12 = cx1f[i][2];
        float r00 = ry0f[i][0], r01 = ry0f[i][1], r02 = ry0f[i][2];
        float r10 = ry1f[i][0], r11 = ry1f[i][1], r12 = ry1f[i][2];
#pragma unroll
        for (int cc = 0; cc < 8; cc++) {
            const float* w = Wp + (size_t)((cbase + cc) * NCLS + i + 1) * 9;
            float w0 = w[0], w1 = w[1], w2 = w[2];
            float w3 = w[3], w4 = w[4], w5 = w[5];
            float w6 = w[6], w7 = w[7], w8 = w[8];
            float s00 = w0 * c00 + w1 * c01 + w2 * c02;
            float s01 = w3 * c00 + w4 * c01 + w5 * c02;
            float s02 = w6 * c00 + w7 * c01 + w8 * c02;
            float s10 = w0 * c10 + w1 * c11 + w2 * c12;
            float s11 = w3 * c10 + w4 * c11 + w5 * c12;
            float s12 = w6 * c10 + w7 * c11 + w8 * c12;
            P[cc][0] += s00 * r00 + s01 * r01 + s02 * r02;  // (y0,x0)
            P[cc][1] += s10 * r00 + s11 * r01 + s12 * r02;  // (y0,x1)
            P[cc][2] += s00 * r10 + s01 * r11 + s02 * r12;  // (y1,x0)
            P[cc][3] += s10 * r10 + s11 * r11 + s12 * r12;  // (y1,x1)
        }
    }

    float acc[NCLS] = {0, 0, 0, 0, 0, 0};
#pragma unroll
    for (int cc = 0; cc < 8; cc++) {
        int c = cbase + cc;
        float p00 = fmaxf(P[cc][0], 0.f);
        float p01 = fmaxf(P[cc][1], 0.f);
        float p10 = fmaxf(P[cc][2], 0.f);
        float p11 = fmaxf(P[cc][3], 0.f);
        float t0 = p00 * (1.f - wy) + p10 * wy;
        float t1 = p01 * (1.f - wy) + p11 * wy;
        float val = t0 * (1.f - wx) + t1 * wx;
        int idx = ((b * CSEM + c) * HS + oy) * HS + x;
        xk[idx] = val;
        float att = enc[idx] * val;
#pragma unroll
        for (int o = 0; o < NCLS; o++) acc[o] += Wa[o * CSEM + c] * att;
    }

    __shared__ float red[NCLS][8][32];
#pragma unroll
    for (int o = 0; o < NCLS; o++) red[o][c0][x] = acc[o];
    __syncthreads();
    if (t < NCLS * 32) {
        int o = t >> 5;
        int xx = t & 31;
        float s = 0.f;
#pragma unroll
        for (int j = 0; j < 8; j++) s += red[o][j][xx];
        part[(((cg * BATCH + b) * NCLS + o) * HS + oy) * HS + xx] = s;
    }
}

// ---------------- Kernel 2: softmax + sag gate --------------------------------
// Grid/block mapping matches k1's xdeck blocks exactly (b,oy,cg -> blockIdx),
// so each block re-reads the SAME 64-channel enc slice its k1 counterpart read
// on the same XCD -> L2 hits instead of HBM re-fetch.
__global__ void k_softmax_sag(const float* __restrict__ part, const float* __restrict__ enc,
                              const float* __restrict__ We, float* __restrict__ out) {
    int blk = blockIdx.x;            // grid = B*32*8
    int cg = blk & 7;
    int oy = (blk >> 3) & 31;
    int b  = blk >> 8;
    int t  = threadIdx.x;

    __shared__ float lg[NCLS][32];
    if (t < NCLS * 32) {
        int o = t >> 5;
        int x = t & 31;
        float s = 0.f;
#pragma unroll
        for (int g = 0; g < 8; g++)
            s += part[(((g * BATCH + b) * NCLS + o) * HS + oy) * HS + x];
        lg[o][x] = s;
    }
    __syncthreads();
    if (t < 32) {
        float l[NCLS];
#pragma unroll
        for (int o = 0; o < NCLS; o++) l[o] = lg[o][t];
        float m = l[0];
#pragma unroll
        for (int o = 1; o < NCLS; o++) m = fmaxf(m, l[o]);
        float sum = 0.f;
#pragma unroll
        for (int o = 0; o < NCLS; o++) { l[o] = expf(l[o] - m); sum += l[o]; }
        float inv = 1.f / sum;
#pragma unroll
        for (int o = 0; o < NCLS; o++) lg[o][t] = l[o] * inv;
    }
    __syncthreads();

    int x4 = (t & 7) << 2;           // float4 along x
    int cc = t >> 3;                 // 0..31
#pragma unroll
    for (int j = 0; j < 2; j++) {
        int c = cg * 64 + cc * 2 + j;
        int idx4 = (((b * CSEM + c) * HS + oy) * HS + x4) >> 2;
        float4 e = reinterpret_cast<const float4*>(enc)[idx4];
        float4 ae = make_float4(0.f, 0.f, 0.f, 0.f);
#pragma unroll
        for (int o = 0; o < NCLS; o++) {
            float w = We[c * NCLS + o];
            ae.x += w * lg[o][x4 + 0];
            ae.y += w * lg[o][x4 + 1];
            ae.z += w * lg[o][x4 + 2];
            ae.w += w * lg[o][x4 + 3];
        }
        float4 r;
        r.x = e.x + 1.f / (1.f + expf(-e.x * ae.x));
        r.y = e.y + 1.f / (1.f + expf(-e.y * ae.y));
        r.z = e.z + 1.f / (1.f + expf(-e.z * ae.z));
        r.w = e.w + 1.f / (1.f + expf(-e.w * ae.w));
        reinterpret_cast<float4*>(out)[idx4] = r;
    }
}

extern "C" void kernel_launch(void* const* d_in, const int* in_sizes, int n_in,
                              void* d_out, int out_size, void* d_ws, size_t ws_size,
                              hipStream_t stream) {
    const float* enc = (const float*)d_in[0];
    const int*   bb  = (const int*)d_in[1];
    const float* Wp  = (const float*)d_in[2];
    const float* bp  = (const float*)d_in[3];
    const float* Wa  = (const float*)d_in[4];
    const float* We  = (const float*)d_in[5];
    float* out = (float*)d_out;
    float* sag = out;
    float* oh  = out + OH_OFF;
    float* xk  = out + XK_OFF;
    // Logit partials live in d_ws (fully rewritten every call).
    float* part = (float*)d_ws;              // 8*B*6*32*32 = 196608 floats

    k_xdeck_raster<<<XDECK_BLOCKS + RASTER_BLOCKS, 256, 0, stream>>>(
        bb, Wp, bp, enc, Wa, xk, part, oh);
    k_softmax_sag <<<XDECK_BLOCKS, 256, 0, stream>>>(part, enc, We, sag);
}